// Round 1
// baseline (679.742 us; speedup 1.0000x reference)
//
#include <hip/hip_runtime.h>

// Segment-average pooling:
//   input  [B=8, C=128, H*W=65536] fp32, labels [B, 65536] int32 in [0, 1024)
//   out    [B, S=1024, C=128] fp32 = per-segment mean over pixels
//
// One kernel. Each block owns (image b, 4-channel chunk c0) and streams all
// 65536 pixels of image b for its 4 channel planes (fully coalesced float4
// loads), accumulating into an LDS array acc[s*5 + {0..3:channel sums, 4:count}]
// via LDS atomics (stride 5 is coprime with the 32 banks). Counts are computed
// redundantly by every chunk-block of the same image — the label plane is only
// 256 KiB and stays in L2/L3 across the 32 re-reads. Epilogue divides and
// stores the final output directly; no global atomics, no workspace.

#define BB 8
#define CC 128
#define NPIX 65536      // 256*256
#define SS 1024
#define THREADS 1024

__global__ __launch_bounds__(THREADS, 1) void seg_avg_kernel(
    const float* __restrict__ inp, const int* __restrict__ seg,
    float* __restrict__ out) {
  __shared__ float acc[SS * 5];   // 20 KiB: [s][c0..c3, count]

  const int b   = blockIdx.x >> 5;         // / (CC/4)
  const int c0  = (blockIdx.x & 31) << 2;  // channel chunk base
  const int tid = threadIdx.x;

  for (int i = tid; i < SS * 5; i += THREADS) acc[i] = 0.0f;
  __syncthreads();

  const float4* __restrict__ p0 =
      reinterpret_cast<const float4*>(inp + ((size_t)b * CC + c0) * NPIX);
  const int4* __restrict__ lab =
      reinterpret_cast<const int4*>(seg + (size_t)b * NPIX);
  const int Q = NPIX / 4;  // 16384 float4 per channel plane

  // 16 iterations: each thread handles 4 consecutive pixels x 4 channels
  #pragma unroll 2
  for (int i = 0; i < NPIX / (4 * THREADS); ++i) {
    const int p = i * THREADS + tid;
    const int4   s4 = lab[p];
    const float4 v0 = p0[p];           // channel c0
    const float4 v1 = p0[p + Q];       // channel c0+1
    const float4 v2 = p0[p + 2 * Q];   // channel c0+2
    const float4 v3 = p0[p + 3 * Q];   // channel c0+3

    const int a0 = s4.x * 5, a1 = s4.y * 5, a2 = s4.z * 5, a3 = s4.w * 5;

    atomicAdd(&acc[a0 + 0], v0.x);
    atomicAdd(&acc[a0 + 1], v1.x);
    atomicAdd(&acc[a0 + 2], v2.x);
    atomicAdd(&acc[a0 + 3], v3.x);
    atomicAdd(&acc[a0 + 4], 1.0f);

    atomicAdd(&acc[a1 + 0], v0.y);
    atomicAdd(&acc[a1 + 1], v1.y);
    atomicAdd(&acc[a1 + 2], v2.y);
    atomicAdd(&acc[a1 + 3], v3.y);
    atomicAdd(&acc[a1 + 4], 1.0f);

    atomicAdd(&acc[a2 + 0], v0.z);
    atomicAdd(&acc[a2 + 1], v1.z);
    atomicAdd(&acc[a2 + 2], v2.z);
    atomicAdd(&acc[a2 + 3], v3.z);
    atomicAdd(&acc[a2 + 4], 1.0f);

    atomicAdd(&acc[a3 + 0], v0.w);
    atomicAdd(&acc[a3 + 1], v1.w);
    atomicAdd(&acc[a3 + 2], v2.w);
    atomicAdd(&acc[a3 + 3], v3.w);
    atomicAdd(&acc[a3 + 4], 1.0f);
  }
  __syncthreads();

  // Epilogue: out[b, s, c0+c] = acc[s][c] / max(count, 1)
  for (int i = tid; i < SS * 4; i += THREADS) {
    const int s = i >> 2;
    const int c = i & 3;
    const float cnt = acc[s * 5 + 4];
    out[((size_t)(b * SS + s)) * CC + c0 + c] =
        acc[s * 5 + c] / fmaxf(cnt, 1.0f);
  }
}

extern "C" void kernel_launch(void* const* d_in, const int* in_sizes, int n_in,
                              void* d_out, int out_size, void* d_ws, size_t ws_size,
                              hipStream_t stream) {
  const float* inp = (const float*)d_in[0];  // [B, C, H, W] fp32
  const int*   seg = (const int*)d_in[1];    // [B, H, W] int32
  float*       out = (float*)d_out;          // [B, S, C] fp32

  const int grid = BB * (CC / 4);  // 256 blocks
  seg_avg_kernel<<<grid, THREADS, 0, stream>>>(inp, seg, out);
}

// Round 2
// 599.855 us; speedup vs baseline: 1.1332x; 1.1332x over previous
//
#include <hip/hip_runtime.h>

// Segment-average pooling:
//   input  [B=8, C=128, H*W=65536] fp32, labels [B, 65536] int32 in [0, 1024)
//   out    [B, S=1024, C=128] fp32 = per-segment mean over pixels
//
// R2 change vs R1: LDS float atomicAdd was compiling to a safe-FP CAS loop
// (~3 cyc/lane-atomic fully serialized -> 424 us with all pipes idle).
// Use unsafeAtomicAdd -> native ds_add_f32 for channel sums, and integer
// atomicAdd -> native ds_add_u32 for counts (stored in the interleaved
// stride-5 slot so every wave-atomic spreads across all 32 banks).

#define BB 8
#define CC 128
#define NPIX 65536      // 256*256
#define SS 1024
#define THREADS 1024

__global__ __launch_bounds__(THREADS, 1) void seg_avg_kernel(
    const float* __restrict__ inp, const int* __restrict__ seg,
    float* __restrict__ out) {
  __shared__ float acc[SS * 5];   // 20 KiB: [s][c0..c3 sums, count(int)]

  const int b   = blockIdx.x >> 5;         // / (CC/4)
  const int c0  = (blockIdx.x & 31) << 2;  // channel chunk base
  const int tid = threadIdx.x;

  for (int i = tid; i < SS * 5; i += THREADS) acc[i] = 0.0f;  // 0 bits == 0 int
  __syncthreads();

  const float4* __restrict__ p0 =
      reinterpret_cast<const float4*>(inp + ((size_t)b * CC + c0) * NPIX);
  const int4* __restrict__ lab =
      reinterpret_cast<const int4*>(seg + (size_t)b * NPIX);
  const int Q = NPIX / 4;  // 16384 float4 per channel plane

  int* iacc = reinterpret_cast<int*>(acc);

  // 16 iterations: each thread handles 4 consecutive pixels x 4 channels
  #pragma unroll 4
  for (int i = 0; i < NPIX / (4 * THREADS); ++i) {
    const int p = i * THREADS + tid;
    const int4   s4 = lab[p];
    const float4 v0 = p0[p];           // channel c0
    const float4 v1 = p0[p + Q];       // channel c0+1
    const float4 v2 = p0[p + 2 * Q];   // channel c0+2
    const float4 v3 = p0[p + 3 * Q];   // channel c0+3

    const int a0 = s4.x * 5, a1 = s4.y * 5, a2 = s4.z * 5, a3 = s4.w * 5;

    unsafeAtomicAdd(&acc[a0 + 0], v0.x);
    unsafeAtomicAdd(&acc[a0 + 1], v1.x);
    unsafeAtomicAdd(&acc[a0 + 2], v2.x);
    unsafeAtomicAdd(&acc[a0 + 3], v3.x);
    atomicAdd(&iacc[a0 + 4], 1);

    unsafeAtomicAdd(&acc[a1 + 0], v0.y);
    unsafeAtomicAdd(&acc[a1 + 1], v1.y);
    unsafeAtomicAdd(&acc[a1 + 2], v2.y);
    unsafeAtomicAdd(&acc[a1 + 3], v3.y);
    atomicAdd(&iacc[a1 + 4], 1);

    unsafeAtomicAdd(&acc[a2 + 0], v0.z);
    unsafeAtomicAdd(&acc[a2 + 1], v1.z);
    unsafeAtomicAdd(&acc[a2 + 2], v2.z);
    unsafeAtomicAdd(&acc[a2 + 3], v3.z);
    atomicAdd(&iacc[a2 + 4], 1);

    unsafeAtomicAdd(&acc[a3 + 0], v0.w);
    unsafeAtomicAdd(&acc[a3 + 1], v1.w);
    unsafeAtomicAdd(&acc[a3 + 2], v2.w);
    unsafeAtomicAdd(&acc[a3 + 3], v3.w);
    atomicAdd(&iacc[a3 + 4], 1);
  }
  __syncthreads();

  // Epilogue: out[b, s, c0+c] = acc[s][c] / max(count, 1)
  for (int i = tid; i < SS * 4; i += THREADS) {
    const int s = i >> 2;
    const int c = i & 3;
    const float cnt = (float)iacc[s * 5 + 4];
    out[((size_t)(b * SS + s)) * CC + c0 + c] =
        acc[s * 5 + c] / fmaxf(cnt, 1.0f);
  }
}

extern "C" void kernel_launch(void* const* d_in, const int* in_sizes, int n_in,
                              void* d_out, int out_size, void* d_ws, size_t ws_size,
                              hipStream_t stream) {
  const float* inp = (const float*)d_in[0];  // [B, C, H, W] fp32
  const int*   seg = (const int*)d_in[1];    // [B, H, W] int32
  float*       out = (float*)d_out;          // [B, S, C] fp32

  const int grid = BB * (CC / 4);  // 256 blocks
  seg_avg_kernel<<<grid, THREADS, 0, stream>>>(inp, seg, out);
}

// Round 3
// 371.818 us; speedup vs baseline: 1.8282x; 1.6133x over previous
//
#include <hip/hip_runtime.h>

// Segment-average pooling, sort-based (zero atomics in the hot kernel).
//   input  [B=8, C=128, N=65536] fp32, labels [B, N] int32 in [0, 1024)
//   out    [B, S=1024, C=128] fp32 segment means
//
// R3: R1/R2 showed gfx950 LDS atomics serialize ~2.5 cyc/lane -> 67M
// lane-atomics is a ~273 us wall. Replace with counting sort:
//   Kernel A: per 4096-px tile, compute each pixel's sorted position
//             (1 LDS atomic per PIXEL, 524k total) + per-tile seg offsets.
//   Kernel B: per (image, 4-ch chunk): per tile, coalesced float4 loads,
//             scatter pixel-vectors to sorted LDS buffer (plain b128 writes),
//             then thread s == segment s serially sums its contiguous run
//             into REGISTERS. Single owner per accumulator -> no atomics.

#define BB 8
#define CC 128
#define NPIX 65536      // 256*256
#define SS 1024
#define TILE 4096
#define NTILES (NPIX / TILE)   // 16
#define THREADS 1024

#define POS_ELEMS (BB * NPIX)           // u16 sorted position within tile
#define OFF_ELEMS (BB * NTILES * SS)    // u16 exclusive offsets per tile

// ---------------- Kernel A: per-tile counting sort metadata ----------------
__global__ __launch_bounds__(THREADS, 1) void sort_kernel(
    const int* __restrict__ seg, unsigned short* __restrict__ pos,
    unsigned short* __restrict__ tileoff) {
  __shared__ unsigned int hist[SS];
  const int b   = blockIdx.x / NTILES;
  const int t   = blockIdx.x % NTILES;
  const int tid = threadIdx.x;

  hist[tid] = 0u;   // THREADS == SS
  __syncthreads();

  const int base = b * NPIX + t * TILE;
  const int4 lab = reinterpret_cast<const int4*>(seg + base)[tid];
  const unsigned int r0 = atomicAdd(&hist[lab.x], 1u);
  const unsigned int r1 = atomicAdd(&hist[lab.y], 1u);
  const unsigned int r2 = atomicAdd(&hist[lab.z], 1u);
  const unsigned int r3 = atomicAdd(&hist[lab.w], 1u);
  __syncthreads();

  const unsigned int cnt = hist[tid];
  // Hillis-Steele inclusive scan in place (read; barrier; write; barrier)
  for (int off = 1; off < SS; off <<= 1) {
    const unsigned int v = (tid >= off) ? hist[tid - off] : 0u;
    __syncthreads();
    hist[tid] += v;
    __syncthreads();
  }
  const unsigned int excl = hist[tid] - cnt;
  tileoff[(b * NTILES + t) * SS + tid] = (unsigned short)excl;
  __syncthreads();
  hist[tid] = excl;
  __syncthreads();

  ushort4 p4;
  p4.x = (unsigned short)(hist[lab.x] + r0);
  p4.y = (unsigned short)(hist[lab.y] + r1);
  p4.z = (unsigned short)(hist[lab.z] + r2);
  p4.w = (unsigned short)(hist[lab.w] + r3);
  reinterpret_cast<ushort4*>(pos + base)[tid] = p4;
}

// ---------------- Kernel B: scatter to sorted LDS, ordered reduce ----------
__global__ __launch_bounds__(THREADS, 1) void aggr_kernel(
    const float* __restrict__ inp, const unsigned short* __restrict__ pos,
    const unsigned short* __restrict__ tileoff, float* __restrict__ out) {
  __shared__ float4 buf[TILE];              // 64 KiB sorted pixel-vectors
  __shared__ unsigned short offl[SS + 1];   // per-tile exclusive offsets

  const int b   = blockIdx.x >> 5;          // / (CC/4)
  const int c0  = (blockIdx.x & 31) << 2;   // channel chunk base
  const int tid = threadIdx.x;              // == segment id for the reduce

  const float4* __restrict__ pl0 =
      reinterpret_cast<const float4*>(inp + ((size_t)b * CC + c0) * NPIX);
  const int Q = NPIX / 4;                   // float4 per channel plane

  float a0 = 0.f, a1 = 0.f, a2 = 0.f, a3 = 0.f;
  int cnt = 0;

  for (int t = 0; t < NTILES; ++t) {
    const int pbase = t * (TILE / 4);
    // 4 consecutive pixels x 4 channel planes, fully coalesced
    const float4 v0 = pl0[pbase + tid];
    const float4 v1 = pl0[pbase + tid + Q];
    const float4 v2 = pl0[pbase + tid + 2 * Q];
    const float4 v3 = pl0[pbase + tid + 3 * Q];
    const ushort4 p4 =
        reinterpret_cast<const ushort4*>(pos + b * NPIX + t * TILE)[tid];
    const unsigned short off_s = tileoff[(b * NTILES + t) * SS + tid];

    __syncthreads();  // previous tile's readers done before overwrite
    if (tid == 0) offl[SS] = (unsigned short)TILE;
    offl[tid] = off_s;
    // transpose 4x4 in regs -> pixel-vectors, scatter to sorted slots
    buf[p4.x] = make_float4(v0.x, v1.x, v2.x, v3.x);
    buf[p4.y] = make_float4(v0.y, v1.y, v2.y, v3.y);
    buf[p4.z] = make_float4(v0.z, v1.z, v2.z, v3.z);
    buf[p4.w] = make_float4(v0.w, v1.w, v2.w, v3.w);
    __syncthreads();

    const int beg = offl[tid];
    const int end = offl[tid + 1];
    cnt += end - beg;
    for (int j = beg; j < end; ++j) {  // contiguous run, single owner
      const float4 v = buf[j];
      a0 += v.x; a1 += v.y; a2 += v.z; a3 += v.w;
    }
  }

  const float inv = 1.0f / (float)max(cnt, 1);
  reinterpret_cast<float4*>(out + ((size_t)(b * SS + tid)) * CC + c0)[0] =
      make_float4(a0 * inv, a1 * inv, a2 * inv, a3 * inv);
}

// ---------------- Fallback (R2): LDS-atomic version, needs no ws -----------
__global__ __launch_bounds__(THREADS, 1) void seg_avg_kernel(
    const float* __restrict__ inp, const int* __restrict__ seg,
    float* __restrict__ out) {
  __shared__ float acc[SS * 5];
  const int b   = blockIdx.x >> 5;
  const int c0  = (blockIdx.x & 31) << 2;
  const int tid = threadIdx.x;
  for (int i = tid; i < SS * 5; i += THREADS) acc[i] = 0.0f;
  __syncthreads();
  const float4* __restrict__ p0 =
      reinterpret_cast<const float4*>(inp + ((size_t)b * CC + c0) * NPIX);
  const int4* __restrict__ lab = reinterpret_cast<const int4*>(seg + (size_t)b * NPIX);
  const int Q = NPIX / 4;
  int* iacc = reinterpret_cast<int*>(acc);
  for (int i = 0; i < NPIX / (4 * THREADS); ++i) {
    const int p = i * THREADS + tid;
    const int4 s4 = lab[p];
    const float4 v0 = p0[p], v1 = p0[p + Q], v2 = p0[p + 2 * Q], v3 = p0[p + 3 * Q];
    const int a0 = s4.x * 5, a1 = s4.y * 5, a2 = s4.z * 5, a3 = s4.w * 5;
    unsafeAtomicAdd(&acc[a0 + 0], v0.x); unsafeAtomicAdd(&acc[a0 + 1], v1.x);
    unsafeAtomicAdd(&acc[a0 + 2], v2.x); unsafeAtomicAdd(&acc[a0 + 3], v3.x);
    atomicAdd(&iacc[a0 + 4], 1);
    unsafeAtomicAdd(&acc[a1 + 0], v0.y); unsafeAtomicAdd(&acc[a1 + 1], v1.y);
    unsafeAtomicAdd(&acc[a1 + 2], v2.y); unsafeAtomicAdd(&acc[a1 + 3], v3.y);
    atomicAdd(&iacc[a1 + 4], 1);
    unsafeAtomicAdd(&acc[a2 + 0], v0.z); unsafeAtomicAdd(&acc[a2 + 1], v1.z);
    unsafeAtomicAdd(&acc[a2 + 2], v2.z); unsafeAtomicAdd(&acc[a2 + 3], v3.z);
    atomicAdd(&iacc[a2 + 4], 1);
    unsafeAtomicAdd(&acc[a3 + 0], v0.w); unsafeAtomicAdd(&acc[a3 + 1], v1.w);
    unsafeAtomicAdd(&acc[a3 + 2], v2.w); unsafeAtomicAdd(&acc[a3 + 3], v3.w);
    atomicAdd(&iacc[a3 + 4], 1);
  }
  __syncthreads();
  for (int i = tid; i < SS * 4; i += THREADS) {
    const int s = i >> 2, c = i & 3;
    const float cntf = (float)iacc[s * 5 + 4];
    out[((size_t)(b * SS + s)) * CC + c0 + c] = acc[s * 5 + c] / fmaxf(cntf, 1.0f);
  }
}

extern "C" void kernel_launch(void* const* d_in, const int* in_sizes, int n_in,
                              void* d_out, int out_size, void* d_ws, size_t ws_size,
                              hipStream_t stream) {
  const float* inp = (const float*)d_in[0];
  const int*   seg = (const int*)d_in[1];
  float*       out = (float*)d_out;

  const size_t need = (size_t)POS_ELEMS * 2 + (size_t)OFF_ELEMS * 2;  // 1.25 MiB
  if (ws_size >= need) {
    unsigned short* pos  = (unsigned short*)d_ws;
    unsigned short* toff = pos + POS_ELEMS;
    sort_kernel<<<BB * NTILES, THREADS, 0, stream>>>(seg, pos, toff);
    aggr_kernel<<<BB * (CC / 4), THREADS, 0, stream>>>(inp, pos, toff, out);
  } else {
    seg_avg_kernel<<<BB * (CC / 4), THREADS, 0, stream>>>(inp, seg, out);
  }
}

// Round 4
// 371.672 us; speedup vs baseline: 1.8289x; 1.0004x over previous
//
#include <hip/hip_runtime.h>

// Segment-average pooling, sort-based, barrier-drain-free pipeline.
//   input  [B=8, C=128, N=65536] fp32, labels [B, N] int32 in [0, 1024)
//   out    [B, S=1024, C=128] fp32 segment means
//
// R4 vs R3: __syncthreads() emits s_waitcnt vmcnt(0) before s_barrier,
// draining the prefetched global loads every tile (m97 barrier-drain).
// Replace with raw `s_waitcnt lgkmcnt(0); s_barrier` (LDS-only ordering)
// and prefetch tile t+1 into registers during tile t's reduce phase ->
// HBM stream stays continuous; tile period ~= max(BW, LDS) not sum.
// Also: sort kernel scan rewritten as shuffle wave-scan (3 barriers vs 20).

#define BB 8
#define CC 128
#define NPIX 65536      // 256*256
#define SS 1024
#define TILE 4096
#define NTILES (NPIX / TILE)   // 16
#define THREADS 1024

#define POS_ELEMS (BB * NPIX)           // u16 sorted position within tile
#define OFF_ELEMS (BB * NTILES * SS)    // u16 exclusive offsets per tile

// Workgroup barrier that orders LDS only — does NOT drain vmcnt, so global
// loads issued before it stay in flight. All waves reach it uniformly.
__device__ __forceinline__ void lds_barrier() {
  asm volatile("s_waitcnt lgkmcnt(0)\n\ts_barrier" ::: "memory");
}

// ---------------- Kernel A: per-tile counting sort metadata ----------------
__global__ __launch_bounds__(THREADS, 1) void sort_kernel(
    const int* __restrict__ seg, unsigned short* __restrict__ pos,
    unsigned short* __restrict__ tileoff) {
  __shared__ unsigned int hist[SS];
  __shared__ unsigned int wsum[16];
  const int b   = blockIdx.x / NTILES;
  const int t   = blockIdx.x % NTILES;
  const int tid = threadIdx.x;

  hist[tid] = 0u;   // THREADS == SS
  __syncthreads();

  const int base = b * NPIX + t * TILE;
  const int4 lab = reinterpret_cast<const int4*>(seg + base)[tid];
  const unsigned int r0 = atomicAdd(&hist[lab.x], 1u);
  const unsigned int r1 = atomicAdd(&hist[lab.y], 1u);
  const unsigned int r2 = atomicAdd(&hist[lab.z], 1u);
  const unsigned int r3 = atomicAdd(&hist[lab.w], 1u);
  __syncthreads();

  const unsigned int cnt = hist[tid];
  // inclusive wave-scan (64 lanes, shuffle, no barriers)
  unsigned int v = cnt;
  #pragma unroll
  for (int off = 1; off < 64; off <<= 1) {
    const unsigned int u = __shfl_up(v, off);
    if ((tid & 63) >= off) v += u;
  }
  const int w = tid >> 6;
  if ((tid & 63) == 63) wsum[w] = v;
  __syncthreads();
  if (tid < 16) {   // scan the 16 wave totals (lanes 0..15 of wave 0)
    unsigned int x = wsum[tid];
    #pragma unroll
    for (int off = 1; off < 16; off <<= 1) {
      const unsigned int u = __shfl_up(x, off);
      if (tid >= off) x += u;
    }
    wsum[tid] = x;  // inclusive
  }
  __syncthreads();
  const unsigned int woff = (w == 0) ? 0u : wsum[w - 1];
  const unsigned int excl = woff + v - cnt;   // exclusive offset of segment tid
  tileoff[(b * NTILES + t) * SS + tid] = (unsigned short)excl;
  hist[tid] = excl;
  __syncthreads();

  ushort4 p4;
  p4.x = (unsigned short)(hist[lab.x] + r0);
  p4.y = (unsigned short)(hist[lab.y] + r1);
  p4.z = (unsigned short)(hist[lab.z] + r2);
  p4.w = (unsigned short)(hist[lab.w] + r3);
  reinterpret_cast<ushort4*>(pos + base)[tid] = p4;
}

// ---------------- Kernel B: scatter to sorted LDS, ordered reduce ----------
__global__ __launch_bounds__(THREADS, 1) void aggr_kernel(
    const float* __restrict__ inp, const unsigned short* __restrict__ pos,
    const unsigned short* __restrict__ tileoff, float* __restrict__ out) {
  __shared__ float4 buf[TILE];              // 64 KiB sorted pixel-vectors
  __shared__ unsigned short offl[SS + 2];   // per-tile exclusive offsets

  const int b   = blockIdx.x >> 5;          // / (CC/4)
  const int c0  = (blockIdx.x & 31) << 2;   // channel chunk base
  const int tid = threadIdx.x;              // == segment id for the reduce

  const float4* __restrict__ pl0 =
      reinterpret_cast<const float4*>(inp + ((size_t)b * CC + c0) * NPIX);
  const ushort4* __restrict__ pos4 =
      reinterpret_cast<const ushort4*>(pos + (size_t)b * NPIX);
  const int Q = NPIX / 4;                   // float4 per channel plane

  float a0 = 0.f, a1 = 0.f, a2 = 0.f, a3 = 0.f;
  int cnt = 0;

  // preload tile 0 into registers
  float4 cv0 = pl0[tid], cv1 = pl0[tid + Q];
  float4 cv2 = pl0[tid + 2 * Q], cv3 = pl0[tid + 3 * Q];
  ushort4 cp4 = pos4[tid];
  unsigned short coff = tileoff[(b * NTILES + 0) * SS + tid];

  for (int t = 0; t < NTILES; ++t) {
    lds_barrier();              // reduce(t-1) readers done; loads stay in flight
    if (tid == 0) offl[SS] = (unsigned short)TILE;
    offl[tid] = coff;
    // transpose 4x4 in regs -> pixel-vectors, scatter to sorted slots
    buf[cp4.x] = make_float4(cv0.x, cv1.x, cv2.x, cv3.x);
    buf[cp4.y] = make_float4(cv0.y, cv1.y, cv2.y, cv3.y);
    buf[cp4.z] = make_float4(cv0.z, cv1.z, cv2.z, cv3.z);
    buf[cp4.w] = make_float4(cv0.w, cv1.w, cv2.w, cv3.w);

    // prefetch tile t+1 (issued now; waited at next scatter's register uses)
    const int tn = (t + 1 < NTILES) ? t + 1 : t;
    const int pn = tn * (TILE / 4) + tid;
    const float4 nv0 = pl0[pn], nv1 = pl0[pn + Q];
    const float4 nv2 = pl0[pn + 2 * Q], nv3 = pl0[pn + 3 * Q];
    const ushort4 np4 = pos4[pn];
    const unsigned short noff = tileoff[(b * NTILES + tn) * SS + tid];

    lds_barrier();              // scatter(t) visible to all waves
    const int beg = offl[tid];
    const int end = offl[tid + 1];
    cnt += end - beg;
    for (int j = beg; j < end; ++j) {  // contiguous run, single owner
      const float4 v = buf[j];
      a0 += v.x; a1 += v.y; a2 += v.z; a3 += v.w;
    }

    cv0 = nv0; cv1 = nv1; cv2 = nv2; cv3 = nv3; cp4 = np4; coff = noff;
  }

  const float inv = 1.0f / (float)max(cnt, 1);
  reinterpret_cast<float4*>(out + ((size_t)(b * SS + tid)) * CC + c0)[0] =
      make_float4(a0 * inv, a1 * inv, a2 * inv, a3 * inv);
}

// ---------------- Fallback (R2): LDS-atomic version, needs no ws -----------
__global__ __launch_bounds__(THREADS, 1) void seg_avg_kernel(
    const float* __restrict__ inp, const int* __restrict__ seg,
    float* __restrict__ out) {
  __shared__ float acc[SS * 5];
  const int b   = blockIdx.x >> 5;
  const int c0  = (blockIdx.x & 31) << 2;
  const int tid = threadIdx.x;
  for (int i = tid; i < SS * 5; i += THREADS) acc[i] = 0.0f;
  __syncthreads();
  const float4* __restrict__ p0 =
      reinterpret_cast<const float4*>(inp + ((size_t)b * CC + c0) * NPIX);
  const int4* __restrict__ lab = reinterpret_cast<const int4*>(seg + (size_t)b * NPIX);
  const int Q = NPIX / 4;
  int* iacc = reinterpret_cast<int*>(acc);
  for (int i = 0; i < NPIX / (4 * THREADS); ++i) {
    const int p = i * THREADS + tid;
    const int4 s4 = lab[p];
    const float4 v0 = p0[p], v1 = p0[p + Q], v2 = p0[p + 2 * Q], v3 = p0[p + 3 * Q];
    const int a0 = s4.x * 5, a1 = s4.y * 5, a2 = s4.z * 5, a3 = s4.w * 5;
    unsafeAtomicAdd(&acc[a0 + 0], v0.x); unsafeAtomicAdd(&acc[a0 + 1], v1.x);
    unsafeAtomicAdd(&acc[a0 + 2], v2.x); unsafeAtomicAdd(&acc[a0 + 3], v3.x);
    atomicAdd(&iacc[a0 + 4], 1);
    unsafeAtomicAdd(&acc[a1 + 0], v0.y); unsafeAtomicAdd(&acc[a1 + 1], v1.y);
    unsafeAtomicAdd(&acc[a1 + 2], v2.y); unsafeAtomicAdd(&acc[a1 + 3], v3.y);
    atomicAdd(&iacc[a1 + 4], 1);
    unsafeAtomicAdd(&acc[a2 + 0], v0.z); unsafeAtomicAdd(&acc[a2 + 1], v1.z);
    unsafeAtomicAdd(&acc[a2 + 2], v2.z); unsafeAtomicAdd(&acc[a2 + 3], v3.z);
    atomicAdd(&iacc[a2 + 4], 1);
    unsafeAtomicAdd(&acc[a3 + 0], v0.w); unsafeAtomicAdd(&acc[a3 + 1], v1.w);
    unsafeAtomicAdd(&acc[a3 + 2], v2.w); unsafeAtomicAdd(&acc[a3 + 3], v3.w);
    atomicAdd(&iacc[a3 + 4], 1);
  }
  __syncthreads();
  for (int i = tid; i < SS * 4; i += THREADS) {
    const int s = i >> 2, c = i & 3;
    const float cntf = (float)iacc[s * 5 + 4];
    out[((size_t)(b * SS + s)) * CC + c0 + c] = acc[s * 5 + c] / fmaxf(cntf, 1.0f);
  }
}

extern "C" void kernel_launch(void* const* d_in, const int* in_sizes, int n_in,
                              void* d_out, int out_size, void* d_ws, size_t ws_size,
                              hipStream_t stream) {
  const float* inp = (const float*)d_in[0];
  const int*   seg = (const int*)d_in[1];
  float*       out = (float*)d_out;

  const size_t need = (size_t)POS_ELEMS * 2 + (size_t)OFF_ELEMS * 2;  // 1.25 MiB
  if (ws_size >= need) {
    unsigned short* pos  = (unsigned short*)d_ws;
    unsigned short* toff = pos + POS_ELEMS;
    sort_kernel<<<BB * NTILES, THREADS, 0, stream>>>(seg, pos, toff);
    aggr_kernel<<<BB * (CC / 4), THREADS, 0, stream>>>(inp, pos, toff, out);
  } else {
    seg_avg_kernel<<<BB * (CC / 4), THREADS, 0, stream>>>(inp, seg, out);
  }
}